// Round 4
// baseline (427.723 us; speedup 1.0000x reference)
//
#include <hip/hip_runtime.h>
#include <hip/hip_bf16.h>

typedef __attribute__((ext_vector_type(4))) float floatx4;
typedef __attribute__((ext_vector_type(8))) short shortx8;

#define NB   16
#define CIN  256
#define COUT 256
#define KW   3
#define LL   4096
#define NR   5
#define QK   768    // CIN*KW
#define NP   65536  // NB*LL

static __device__ __forceinline__ unsigned short bf16bits(float f) {
    __hip_bfloat16 h = __float2bfloat16(f);
    return __builtin_bit_cast(unsigned short, h);
}

// ---------------- K0b: weights -> bf16, M-order m = (o>>4)*80 + r*16 + (o&15), q' = k*256+cin ----------------
__global__ void k_wprep(const float* __restrict__ bk, __hip_bfloat16* __restrict__ wb) {
    int i = blockIdx.x * 256 + threadIdx.x;
    if (i >= NR * COUT * QK) return;
    int m = i / QK, q = i % QK;
    int o = (m / 80) * 16 + (m & 15);
    int r = (m % 80) / 16;
    int k = q >> 8, cin = q & 255;
    wb[i] = __float2bfloat16(bk[((r * COUT + o) * CIN + cin) * KW + k]);
}

// ---------------- K1: fused controller (fr) + transpose-to-bf16 (xt) ----------------
// 64 positions/block. xsh stored [col][cin] (pad 133: lane-stride 5 mod 32 -> free reads).
__global__ void k_prep(const float* __restrict__ x, const float* __restrict__ cw,
                       const float* __restrict__ cb, float* __restrict__ fr,
                       __hip_bfloat16* __restrict__ xt) {
    __shared__ float xsh[68][133];     // 36176 B  (cols l0-4..l0+63, cins of current half)
    __shared__ float cws[QK * NR];     // 15360 B
    __shared__ float part[4][64][NR];  // 5120 B
    int p0 = blockIdx.x * 64;
    int b = p0 >> 12, l0 = p0 & (LL - 1);
    int tid = threadIdx.x, lane = tid & 63, wid = tid >> 6;
    for (int i = tid; i < QK * NR; i += 256) cws[i] = cw[i];
    float lg[NR] = {0.f, 0.f, 0.f, 0.f, 0.f};
    for (int ch = 0; ch < 2; ++ch) {
        __syncthreads();
        // stage cins [ch*128, ch*128+128), cols l0-4 .. l0+63 (global-coalesced float4)
        for (int i = tid; i < 128 * 17; i += 256) {
            int cl = i / 17, c4 = (i % 17) * 4;
            int gl = l0 - 4 + c4;
            float4 v = make_float4(0.f, 0.f, 0.f, 0.f);
            if (gl >= 0) v = *(const float4*)&x[((size_t)(b * CIN + ch * 128 + cl)) * LL + gl];
            xsh[c4 + 0][cl] = v.x;
            xsh[c4 + 1][cl] = v.y;
            xsh[c4 + 2][cl] = v.z;
            xsh[c4 + 3][cl] = v.w;
        }
        __syncthreads();
        // emit xt for this half: 64 pos x 128 cins, coalesced ushort4 stores
        #pragma unroll
        for (int j = 0; j < 8; ++j) {
            int i2 = tid + j * 256;
            int p = i2 >> 5, c4 = (i2 & 31) * 4;
            ushort4 u;
            u.x = bf16bits(xsh[p + 4][c4 + 0]);
            u.y = bf16bits(xsh[p + 4][c4 + 1]);
            u.z = bf16bits(xsh[p + 4][c4 + 2]);
            u.w = bf16bits(xsh[p + 4][c4 + 3]);
            *(ushort4*)&xt[((size_t)(b * LL + l0 + p)) * CIN + ch * 128 + c4] = u;
        }
        // controller partial dot-products
        #pragma unroll 8
        for (int r = 0; r < 32; ++r) {
            int cl = wid * 32 + r;
            int cg = ch * 128 + cl;
            float x0 = xsh[lane + 2][cl], x1 = xsh[lane + 3][cl], x2 = xsh[lane + 4][cl];
            const float* w = &cws[cg * 3 * NR];
            #pragma unroll
            for (int n = 0; n < NR; ++n)
                lg[n] += x0 * w[n] + x1 * w[NR + n] + x2 * w[2 * NR + n];
        }
    }
    #pragma unroll
    for (int n = 0; n < NR; ++n) part[wid][lane][n] = lg[n];
    __syncthreads();
    if (tid < 64) {
        float l2[NR];
        #pragma unroll
        for (int n = 0; n < NR; ++n)
            l2[n] = cb[n] + part[0][tid][n] + part[1][tid][n] + part[2][tid][n] + part[3][tid][n];
        float m = l2[0];
        #pragma unroll
        for (int n = 1; n < NR; ++n) m = fmaxf(m, l2[n]);
        float e[NR], s = 0.f;
        #pragma unroll
        for (int n = 0; n < NR; ++n) { e[n] = __expf(l2[n] - m); s += e[n]; }
        float inv = 1.f / s;
        #pragma unroll
        for (int n = 0; n < NR; ++n) fr[(size_t)(p0 + tid) * NR + n] = e[n] * inv;
    }
}

// ---------------- K2: fused conv + mixture. 512 threads, 8 waves x (M80 x N32) ----------------
// Same swizzled single-LDS-buffer phase structure as R3, but 8 waves -> 40 accs/wave,
// ~120 regs -> 4 waves/SIMD (16 waves/CU with 2 blocks/CU on LDS).
#define XS_CHUNKS 2064              // 258 rows * 8 chunks
#define WS_CHUNKS 1920              // 240 strips * 8 chunks
#define XS_SHORTS (XS_CHUNKS * 8)   // 16512
__global__ __launch_bounds__(512, 4)
void k_conv(const __hip_bfloat16* __restrict__ xt, const __hip_bfloat16* __restrict__ wb,
            const float* __restrict__ fr, const float* __restrict__ bias,
            float* __restrict__ out) {
    __shared__ __align__(16) short lds[XS_SHORTS + WS_CHUNKS * 8];  // 63744 B
    __shared__ float bs[80];

    int g = blockIdx.x;
    int pt = ((g >> 7) << 3) | (g & 7);   // XCD swizzle
    int y  = (g >> 3) & 15;
    int p0 = pt * 256;
    int m0 = y * 80, o0 = y * 16;
    int b = p0 >> 12, l0 = p0 & (LL - 1);
    int tid = threadIdx.x;
    int lane = tid & 63, wn = tid >> 6;   // 8 waves split N into 8 x 32
    int quad = lane >> 4, l16 = lane & 15;

    const __hip_bfloat16* xb = xt + (size_t)b * (LL * CIN);

    if (tid < 80) bs[tid] = bias[(tid >> 4) * COUT + o0 + (tid & 15)];

    // phase-invariant LDS frag offsets (shorts)
    int boffb[3], aoffb[3];
    #pragma unroll
    for (int kh = 0; kh < 3; ++kh) {
        int row0 = wn * 32 + l16 + kh;
        boffb[kh] = row0 * 64 + (quad ^ (row0 & 7)) * 8;            // + nf*1024
        int s0 = kh * 80 + l16;
        aoffb[kh] = XS_SHORTS + s0 * 64 + (quad ^ (l16 & 7)) * 8;   // + mf*1024
    }

    floatx4 acc[NR][2];
    #pragma unroll
    for (int mf = 0; mf < NR; ++mf)
        #pragma unroll
        for (int nf = 0; nf < 2; ++nf)
            acc[mf][nf] = (floatx4){0.f, 0.f, 0.f, 0.f};

    uint4 sx[5], sw[4];
    auto load_regs = [&](int h) {
        #pragma unroll
        for (int j = 0; j < 5; ++j) {
            int i = tid + j * 512;
            if (j < 4 || i < XS_CHUNKS) {
                int row = i >> 3, cg = (i & 7) ^ (row & 7);
                int gl = l0 - 2 + row;
                int gls = gl < 0 ? 0 : gl;
                uint4 v = *(const uint4*)(xb + (size_t)gls * CIN + h * 64 + cg * 8);
                if (gl < 0) v = make_uint4(0u, 0u, 0u, 0u);
                sx[j] = v;
            }
        }
        #pragma unroll
        for (int j = 0; j < 4; ++j) {
            int i = tid + j * 512;
            if (j < 3 || i < WS_CHUNKS) {
                int s = i >> 3, cg = (i & 7) ^ (s & 7);
                int kh = s / 80, m = s - kh * 80;
                sw[j] = *(const uint4*)(wb + ((m0 + m) * QK + kh * 256 + h * 64 + cg * 8));
            }
        }
    };
    auto store_lds = [&]() {
        #pragma unroll
        for (int j = 0; j < 5; ++j) {
            int i = tid + j * 512;
            if (j < 4 || i < XS_CHUNKS) *(uint4*)&lds[i * 8] = sx[j];
        }
        #pragma unroll
        for (int j = 0; j < 4; ++j) {
            int i = tid + j * 512;
            if (j < 3 || i < WS_CHUNKS) *(uint4*)&lds[XS_SHORTS + i * 8] = sw[j];
        }
    };

    load_regs(0);
    for (int h = 0; h < 4; ++h) {
        store_lds();                 // consumes prefetch regs
        if (h < 3) load_regs(h + 1); // next phase's loads in flight across barrier+compute
        __syncthreads();
        #pragma unroll
        for (int kh = 0; kh < 3; ++kh) {
            #pragma unroll
            for (int csi = 0; csi < 2; ++csi) {
                int xr = csi * 32;   // phys-chunk bit2 toggle
                shortx8 bfrag[2], afrag[NR];
                #pragma unroll
                for (int nf = 0; nf < 2; ++nf)
                    bfrag[nf] = *(const shortx8*)&lds[(boffb[kh] + nf * 1024) ^ xr];
                #pragma unroll
                for (int mf = 0; mf < NR; ++mf)
                    afrag[mf] = *(const shortx8*)&lds[(aoffb[kh] + mf * 1024) ^ xr];
                #pragma unroll
                for (int mf = 0; mf < NR; ++mf)
                    #pragma unroll
                    for (int nf = 0; nf < 2; ++nf)
                        acc[mf][nf] = __builtin_amdgcn_mfma_f32_16x16x32_bf16(
                            afrag[mf], bfrag[nf], acc[mf][nf], 0, 0, 0);
            }
        }
        __syncthreads();
    }

    // epilogue
    #pragma unroll
    for (int nf = 0; nf < 2; ++nf) {
        int colp = wn * 32 + nf * 16 + l16;
        const float* fp = fr + (size_t)(p0 + colp) * NR;
        float f0 = fp[0], f1 = fp[1], f2 = fp[2], f3 = fp[3], f4 = fp[4];
        #pragma unroll
        for (int j = 0; j < 4; ++j) {
            int olo = quad * 4 + j;
            float v = f0 * (acc[0][nf][j] + bs[0 * 16 + olo])
                    + f1 * (acc[1][nf][j] + bs[1 * 16 + olo])
                    + f2 * (acc[2][nf][j] + bs[2 * 16 + olo])
                    + f3 * (acc[3][nf][j] + bs[3 * 16 + olo])
                    + f4 * (acc[4][nf][j] + bs[4 * 16 + olo]);
            out[((size_t)(b * COUT + o0 + olo)) * LL + l0 + colp] = v;
        }
    }
}

extern "C" void kernel_launch(void* const* d_in, const int* in_sizes, int n_in,
                              void* d_out, int out_size, void* d_ws, size_t ws_size,
                              hipStream_t stream) {
    const float* x  = (const float*)d_in[0];
    const float* bk = (const float*)d_in[1];
    const float* bb = (const float*)d_in[2];
    const float* cw = (const float*)d_in[3];
    const float* cb = (const float*)d_in[4];
    float* out = (float*)d_out;

    char* ws = (char*)d_ws;
    __hip_bfloat16* xt = (__hip_bfloat16*)ws;                         // 33,554,432 B
    __hip_bfloat16* wb = (__hip_bfloat16*)(ws + 33554432);            //  1,966,080 B
    float*          fr = (float*)(ws + 33554432 + 1966080);           //  1,310,720 B

    k_prep<<<dim3(NP / 64), dim3(256), 0, stream>>>(x, cw, cb, fr, xt);
    k_wprep<<<dim3((NR * COUT * QK + 255) / 256), dim3(256), 0, stream>>>(bk, wb);
    k_conv<<<dim3(NP / 256 * (COUT / 16)), dim3(512), 0, stream>>>(xt, wb, fr, bb, out);
}